// Round 1
// baseline (430.030 us; speedup 1.0000x reference)
//
#include <hip/hip_runtime.h>
#include <math.h>

#define DIM 256
#define WIN 100
#define NEP 10000
#define D1 1024   // DIM*4
#define D2 512    // DIM*2
#define DQ 25600  // DIM*WIN
#define DE 4096   // COMP*DIM
#define KMAX 8
#define P1_BLOCKS 800
#define P4_BLOCKS 64

// ---- workspace layout (float element offsets) ----
#define OFF_P1   0                                   // [800][1024]
#define OFF_P1B  (OFF_P1 + P1_BLOCKS * D1)           // [16][1024]
#define OFF_H1   (OFF_P1B + 16 * D1)                 // [1024]
#define OFF_P2   (OFF_H1 + D1)                       // [32][512]
#define OFF_H2   (OFF_P2 + 32 * D2)                  // [512]
#define OFF_P3   (OFF_H2 + D2)                       // [16][4096]
#define OFF_ENC  (OFF_P3 + 16 * DE)                  // [4096]
#define OFF_QN2  (OFF_ENC + DE)                      // [1] (padded to 4)
#define OFF_SIMS (OFF_QN2 + 4)                       // [10000]
#define OFF_IDX  (OFF_SIMS + NEP)                    // [8] ints
#define OFF_P4   (OFF_IDX + 8)                       // [64][KMAX][512]
#define OFF_D    (OFF_P4 + P4_BLOCKS * KMAX * D2)    // [KMAX][512]
#define OFF_P5   (OFF_D + KMAX * D2)                 // [16][256]

__device__ __forceinline__ float gelu_exact(float x) {
    return 0.5f * x * (1.0f + erff(x * 0.7071067811865476f));
}

// block-wide sum; every thread returns the same value. red[] must hold nthreads/64 floats.
template <int NTHREADS>
__device__ __forceinline__ float block_sum(float v, float* red) {
    for (int o = 32; o > 0; o >>= 1) v += __shfl_down(v, o);
    const int wid = threadIdx.x >> 6;
    __syncthreads();
    if ((threadIdx.x & 63) == 0) red[wid] = v;
    __syncthreads();
    float s = 0.f;
    constexpr int NW = NTHREADS >> 6;
    #pragma unroll
    for (int w = 0; w < NW; ++w) s += red[w];
    return s;
}

// ---- K1: q @ W1 partials. grid 800, rows 32/block, cols 1024 via float4 ----
__global__ __launch_bounds__(256) void k1_gemv1(const float* __restrict__ q,
                                                const float* __restrict__ W1,
                                                float* __restrict__ ws) {
    __shared__ float sq[32];
    const int blk = blockIdx.x, t = threadIdx.x;
    const int i0 = blk * 32;
    if (t < 32) sq[t] = q[i0 + t];
    __syncthreads();
    float4 acc = {0.f, 0.f, 0.f, 0.f};
    #pragma unroll 4
    for (int i = 0; i < 32; ++i) {
        const float qv = sq[i];
        const float4 w = ((const float4*)(W1 + (size_t)(i0 + i) * D1))[t];
        acc.x += qv * w.x; acc.y += qv * w.y; acc.z += qv * w.z; acc.w += qv * w.w;
    }
    ((float4*)(ws + OFF_P1 + (size_t)blk * D1))[t] = acc;
}

// ---- K2a: reduce 800 partials -> 16.  grid 64 = 16 pc x 4 cc ----
__global__ __launch_bounds__(256) void k2a_reduce(float* __restrict__ ws) {
    const int b = blockIdx.x, pc = b >> 2, cc = b & 3;
    const int col = cc * 256 + threadIdx.x;
    float s = 0.f;
    for (int p = pc * 50; p < pc * 50 + 50; ++p) s += ws[OFF_P1 + (size_t)p * D1 + col];
    ws[OFF_P1B + pc * D1 + col] = s;
}

// ---- K2b: final reduce + bias + GELU + LN -> h1 ----
__global__ __launch_bounds__(1024) void k2b_h1(const float* __restrict__ b1,
                                               const float* __restrict__ g1,
                                               const float* __restrict__ be1,
                                               float* __restrict__ ws) {
    __shared__ float red[16];
    const int t = threadIdx.x;
    float s = 0.f;
    #pragma unroll
    for (int p = 0; p < 16; ++p) s += ws[OFF_P1B + p * D1 + t];
    const float x = gelu_exact(s + b1[t]);
    const float mu = block_sum<1024>(x, red) * (1.f / D1);
    const float d = x - mu;
    const float var = block_sum<1024>(d * d, red) * (1.f / D1);
    ws[OFF_H1 + t] = d * rsqrtf(var + 1e-5f) * g1[t] + be1[t];
}

// ---- K4: h1 @ W2 partials. grid 32 (rows 32/block), cols 512 via float2 ----
__global__ __launch_bounds__(256) void k4_gemv2(const float* __restrict__ W2,
                                                float* __restrict__ ws) {
    __shared__ float sh[32];
    const int blk = blockIdx.x, t = threadIdx.x;
    const int i0 = blk * 32;
    if (t < 32) sh[t] = ws[OFF_H1 + i0 + t];
    __syncthreads();
    float2 acc = {0.f, 0.f};
    #pragma unroll 4
    for (int i = 0; i < 32; ++i) {
        const float hv = sh[i];
        const float2 w = ((const float2*)(W2 + (size_t)(i0 + i) * D2))[t];
        acc.x += hv * w.x; acc.y += hv * w.y;
    }
    ((float2*)(ws + OFF_P2 + blk * D2))[t] = acc;
}

// ---- K5: reduce + bias + GELU + LN -> h2 ----
__global__ __launch_bounds__(512) void k5_h2(const float* __restrict__ b2,
                                             const float* __restrict__ g2,
                                             const float* __restrict__ be2,
                                             float* __restrict__ ws) {
    __shared__ float red[8];
    const int t = threadIdx.x;
    float s = 0.f;
    #pragma unroll
    for (int p = 0; p < 32; ++p) s += ws[OFF_P2 + p * D2 + t];
    const float x = gelu_exact(s + b2[t]);
    const float mu = block_sum<512>(x, red) * (1.f / D2);
    const float d = x - mu;
    const float var = block_sum<512>(d * d, red) * (1.f / D2);
    ws[OFF_H2 + t] = d * rsqrtf(var + 1e-5f) * g2[t] + be2[t];
}

// ---- K6: h2 @ W3 partials. grid 64 = 16 rc x 4 cc ----
__global__ __launch_bounds__(256) void k6_gemv3(const float* __restrict__ W3,
                                                float* __restrict__ ws) {
    __shared__ float sh[32];
    const int b = blockIdx.x, rc = b >> 2, cc = b & 3;
    const int t = threadIdx.x;
    const int i0 = rc * 32;
    if (t < 32) sh[t] = ws[OFF_H2 + i0 + t];
    __syncthreads();
    float4 acc = {0.f, 0.f, 0.f, 0.f};
    #pragma unroll 4
    for (int i = 0; i < 32; ++i) {
        const float hv = sh[i];
        const float4 w = ((const float4*)(W3 + (size_t)(i0 + i) * DE + cc * 1024))[t];
        acc.x += hv * w.x; acc.y += hv * w.y; acc.z += hv * w.z; acc.w += hv * w.w;
    }
    ((float4*)(ws + OFF_P3 + rc * DE + cc * 1024))[t] = acc;
}

// ---- K7: reduce -> enc + b3; accumulate ||enc||^2 ----
__global__ __launch_bounds__(256) void k7_enc(const float* __restrict__ b3,
                                              float* __restrict__ ws) {
    __shared__ float red[4];
    const int col = blockIdx.x * 256 + threadIdx.x;
    float s = 0.f;
    #pragma unroll
    for (int p = 0; p < 16; ++p) s += ws[OFF_P3 + p * DE + col];
    s += b3[col];
    ws[OFF_ENC + col] = s;
    const float ss = block_sum<256>(s * s, red);
    if (threadIdx.x == 0) atomicAdd(ws + OFF_QN2, ss);
}

// ---- K8: cosine sims. one block per episode ----
__global__ __launch_bounds__(256) void k8_sims(const float* __restrict__ ep,
                                               float* __restrict__ ws) {
    __shared__ float redd[4];
    __shared__ float reds[4];
    const int e = blockIdx.x, t = threadIdx.x;
    const float4* row = (const float4*)(ep + (size_t)e * DE);
    const float4* encv = (const float4*)(ws + OFF_ENC);
    float dot = 0.f, ss = 0.f;
    #pragma unroll
    for (int c = 0; c < 4; ++c) {
        const float4 a = row[t + 256 * c];
        const float4 b = encv[t + 256 * c];
        dot += a.x * b.x + a.y * b.y + a.z * b.z + a.w * b.w;
        ss  += a.x * a.x + a.y * a.y + a.z * a.z + a.w * a.w;
    }
    for (int o = 32; o > 0; o >>= 1) {
        dot += __shfl_down(dot, o);
        ss  += __shfl_down(ss, o);
    }
    const int wid = t >> 6;
    if ((t & 63) == 0) { redd[wid] = dot; reds[wid] = ss; }
    __syncthreads();
    if (t == 0) {
        const float dsum = redd[0] + redd[1] + redd[2] + redd[3];
        const float ssum = reds[0] + reds[1] + reds[2] + reds[3];
        const float qn = fmaxf(sqrtf(ws[OFF_QN2]), 1e-8f);
        const float en = fmaxf(sqrtf(ssum), 1e-8f);
        ws[OFF_SIMS + e] = dsum / (qn * en);
    }
}

// ---- K9: top-k via k iterated argmax passes (single block) ----
__global__ __launch_bounds__(256) void k9_topk(const int* __restrict__ kptr,
                                               float* __restrict__ ws) {
    __shared__ float bv[256];
    __shared__ int   bi[256];
    const int t = threadIdx.x;
    const int k = min(*kptr, KMAX);
    int* idx = (int*)(ws + OFF_IDX);
    for (int p = 0; p < k; ++p) {
        float best = -1e30f; int besti = 0;
        for (int j = t; j < NEP; j += 256) {
            const float v = ws[OFF_SIMS + j];
            if (v > best) { best = v; besti = j; }
        }
        bv[t] = best; bi[t] = besti;
        __syncthreads();
        for (int o = 128; o > 0; o >>= 1) {
            if (t < o) {
                const float v2 = bv[t + o]; const int i2 = bi[t + o];
                if (v2 > bv[t] || (v2 == bv[t] && i2 < bi[t])) { bv[t] = v2; bi[t] = i2; }
            }
            __syncthreads();
        }
        if (t == 0) { idx[p] = bi[0]; ws[OFF_SIMS + bi[0]] = -1e30f; }
        __syncthreads();
    }
}

// ---- K10: sel @ Wd1 partials. grid 64 (i-chunks of 64), k rows at once ----
__global__ __launch_bounds__(256) void k10_dec1(const float* __restrict__ ep,
                                                const float* __restrict__ Wd1,
                                                const int* __restrict__ kptr,
                                                float* __restrict__ ws) {
    __shared__ float ssel[KMAX][64];
    const int blk = blockIdx.x, t = threadIdx.x;
    const int k = min(*kptr, KMAX);
    const int* idx = (const int*)(ws + OFF_IDX);
    const int i0 = blk * 64;
    for (int x = t; x < k * 64; x += 256) {
        const int r = x >> 6, ii = x & 63;
        ssel[r][ii] = ep[(size_t)idx[r] * DE + i0 + ii];
    }
    __syncthreads();
    float2 acc[KMAX];
    #pragma unroll
    for (int r = 0; r < KMAX; ++r) acc[r] = make_float2(0.f, 0.f);
    for (int i = 0; i < 64; ++i) {
        const float2 w = ((const float2*)(Wd1 + (size_t)(i0 + i) * D2))[t];
        #pragma unroll
        for (int r = 0; r < KMAX; ++r) {
            if (r < k) { const float sv = ssel[r][i]; acc[r].x += sv * w.x; acc[r].y += sv * w.y; }
        }
    }
    for (int r = 0; r < k; ++r)
        ((float2*)(ws + OFF_P4 + ((size_t)blk * KMAX + r) * D2))[t] = acc[r];
}

// ---- K11: reduce + bias + GELU + LN per selected row -> d[r][512] ----
__global__ __launch_bounds__(256) void k11_d(const float* __restrict__ bd1,
                                             const float* __restrict__ gd,
                                             const float* __restrict__ bed,
                                             const int* __restrict__ kptr,
                                             float* __restrict__ ws) {
    __shared__ float red[4];
    const int r = blockIdx.x, t = threadIdx.x;
    const int k = min(*kptr, KMAX);
    if (r >= k) return;
    float2 s = {0.f, 0.f};
    for (int c = 0; c < P4_BLOCKS; ++c) {
        const float2 p = ((const float2*)(ws + OFF_P4 + ((size_t)c * KMAX + r) * D2))[t];
        s.x += p.x; s.y += p.y;
    }
    const float x0 = gelu_exact(s.x + bd1[2 * t]);
    const float x1 = gelu_exact(s.y + bd1[2 * t + 1]);
    const float mu = block_sum<256>(x0 + x1, red) * (1.f / D2);
    const float d0 = x0 - mu, d1 = x1 - mu;
    const float var = block_sum<256>(d0 * d0 + d1 * d1, red) * (1.f / D2);
    const float inv = rsqrtf(var + 1e-5f);
    ws[OFF_D + r * D2 + 2 * t]     = d0 * inv * gd[2 * t] + bed[2 * t];
    ws[OFF_D + r * D2 + 2 * t + 1] = d1 * inv * gd[2 * t + 1] + bed[2 * t + 1];
}

// ---- K12: dbar @ Wd2 partials. grid 16 (i-chunks of 32) ----
__global__ __launch_bounds__(256) void k12_dec2(const float* __restrict__ Wd2,
                                                const int* __restrict__ kptr,
                                                float* __restrict__ ws) {
    __shared__ float sdb[32];
    const int b = blockIdx.x, t = threadIdx.x;
    const int k = min(*kptr, KMAX);
    if (t < 32) {
        float s = 0.f;
        for (int r = 0; r < k; ++r) s += ws[OFF_D + r * D2 + b * 32 + t];
        sdb[t] = s / (float)k;
    }
    __syncthreads();
    float acc = 0.f;
    #pragma unroll 8
    for (int i = 0; i < 32; ++i) acc += sdb[i] * Wd2[(size_t)(b * 32 + i) * DIM + t];
    ws[OFF_P5 + b * DIM + t] = acc;
}

// ---- K13: final sum + bd2 -> out ----
__global__ __launch_bounds__(256) void k13_out(const float* __restrict__ bd2,
                                               const float* __restrict__ ws,
                                               float* __restrict__ out) {
    const int t = threadIdx.x;
    float s = bd2[t];
    #pragma unroll
    for (int b = 0; b < 16; ++b) s += ws[OFF_P5 + b * DIM + t];
    out[t] = s;
}

extern "C" void kernel_launch(void* const* d_in, const int* in_sizes, int n_in,
                              void* d_out, int out_size, void* d_ws, size_t ws_size,
                              hipStream_t stream) {
    const float* q   = (const float*)d_in[0];
    const float* ep  = (const float*)d_in[1];
    const float* W1  = (const float*)d_in[2];
    const float* b1  = (const float*)d_in[3];
    const float* g1  = (const float*)d_in[4];
    const float* be1 = (const float*)d_in[5];
    const float* W2  = (const float*)d_in[6];
    const float* b2  = (const float*)d_in[7];
    const float* g2  = (const float*)d_in[8];
    const float* be2 = (const float*)d_in[9];
    const float* W3  = (const float*)d_in[10];
    const float* b3  = (const float*)d_in[11];
    const float* Wd1 = (const float*)d_in[12];
    const float* bd1 = (const float*)d_in[13];
    const float* gd  = (const float*)d_in[14];
    const float* bed = (const float*)d_in[15];
    const float* Wd2 = (const float*)d_in[16];
    const float* bd2 = (const float*)d_in[17];
    const int*   kp  = (const int*)d_in[18];
    float* ws  = (float*)d_ws;
    float* out = (float*)d_out;

    hipMemsetAsync(ws + OFF_QN2, 0, sizeof(float), stream);
    k1_gemv1<<<P1_BLOCKS, 256, 0, stream>>>(q, W1, ws);
    k2a_reduce<<<64, 256, 0, stream>>>(ws);
    k2b_h1<<<1, 1024, 0, stream>>>(b1, g1, be1, ws);
    k4_gemv2<<<32, 256, 0, stream>>>(W2, ws);
    k5_h2<<<1, 512, 0, stream>>>(b2, g2, be2, ws);
    k6_gemv3<<<64, 256, 0, stream>>>(W3, ws);
    k7_enc<<<16, 256, 0, stream>>>(b3, ws);
    k8_sims<<<NEP, 256, 0, stream>>>(ep, ws);
    k9_topk<<<1, 256, 0, stream>>>(kp, ws);
    k10_dec1<<<P4_BLOCKS, 256, 0, stream>>>(ep, Wd1, kp, ws);
    k11_d<<<KMAX, 256, 0, stream>>>(bd1, gd, bed, kp, ws);
    k12_dec2<<<16, 256, 0, stream>>>(Wd2, kp, ws);
    k13_out<<<1, 256, 0, stream>>>(bd2, ws, out);
}